// Round 12
// baseline (1738.300 us; speedup 1.0000x reference)
//
#include <hip/hip_runtime.h>

#define N_NODES 50000
#define N_EDGES 800000
#define HID 128
#define DEPTH 10
#define N_GRAPHS 512
#define IN_F 32

#define BM 128                       // GEMM rows per block
#define GBLK (50048 / BM)            // 391
#define PADN 50048

#define ROWW 256                     // interleaved row width in shorts: [H 128 | L 128]

#define SB 256                       // scan block size
#define NSB ((N_NODES + SB - 1) / SB)     // 196

#define NBIN 8                       // dst bins == XCDs
#define BINW ((N_NODES + NBIN - 1) / NBIN)   // 6250
#define NCH 500                      // edge chunks per bin
#define CHSZ (N_EDGES / NCH)         // 1600

#define NBT 20                       // B tiles per layer (5 terms x 4 kc)
#define NAST 12                      // A stages (3 planes x 4 kc): aggH, aggL, hH
#define PACK_CHUNKS (DEPTH * NBT * 512)

typedef __attribute__((ext_vector_type(8))) short short8;
typedef __attribute__((ext_vector_type(4))) float f32x4;
typedef __attribute__((ext_vector_type(4))) unsigned uint4v;

__device__ __forceinline__ float bf2f(short u) {
    union { unsigned i; float f; } v; v.i = ((unsigned)(unsigned short)u) << 16; return v.f;
}
__device__ __forceinline__ short f2bf(float f) {
    union { float f; unsigned i; } v; v.f = f;
    unsigned r = (v.i + 0x7FFFu + ((v.i >> 16) & 1u)) >> 16;
    return (short)r;
}
__device__ __forceinline__ unsigned pack2(short lo, short hi) {
    return ((unsigned)(unsigned short)hi << 16) | (unsigned)(unsigned short)lo;
}

// -------------------- weight pack: per-A-stage B-tile order --------------------
// Tiles t (0..19): t<8:  (rel,  kc=t>>1,      lo=t&1)   [aggH stages: relH,relL]
//                  8-11: (rel,  kc=t-8,       lo=0)     [aggL stages: relH]
//                  12-19:(root, kc=(t-12)>>1, lo=t&1)   [hH stages: rootH,rootL]
__global__ __launch_bounds__(256) void pack_weights(
    const float* __restrict__ Wrel, const float* __restrict__ Wroot,
    short* __restrict__ Bp) {
    int idx = blockIdx.x * 256 + threadIdx.x;
    if (idx >= PACK_CHUNKS) return;
    int layer = idx / (NBT * 512);
    int rem = idx - layer * NBT * 512;
    int t = rem >> 9;
    int c = rem & 511;
    int kslot = c >> 7, n = c & 127;
    int kc, lo;
    const float* W;
    if (t < 8)       { kc = t >> 1;        W = Wrel;  lo = t & 1; }
    else if (t < 12) { kc = t - 8;         W = Wrel;  lo = 0; }
    else             { kc = (t - 12) >> 1; W = Wroot; lo = t & 1; }
    W += (size_t)layer * HID * HID;
    short out[8];
#pragma unroll
    for (int j = 0; j < 8; ++j) {
        int k = kc * 32 + kslot * 8 + j;
        float v = W[(size_t)k * HID + n];
        short hi = f2bf(v);
        if (lo) { v = v - bf2f(hi); hi = f2bf(v); }
        out[j] = hi;
    }
    *reinterpret_cast<short8*>(Bp + (size_t)idx * 8) = *reinterpret_cast<short8*>(out);
}

// -------------------- embed: h = x @ W_embed -> hIL rows + hSl slice-major H ----
__global__ __launch_bounds__(128) void embed_kernel(
    const float* __restrict__ x, const float* __restrict__ W,
    short* __restrict__ hIL, short* __restrict__ hSl) {
    __shared__ float Ws[IN_F * HID];
    int t = threadIdx.x;
    for (int i = t; i < IN_F * HID; i += 128) Ws[i] = W[i];
    __syncthreads();
    int nbeg = blockIdx.x * 50;
    for (int n = nbeg; n < nbeg + 50; ++n) {
        float acc = 0.f;
#pragma unroll
        for (int k = 0; k < IN_F; ++k)
            acc += x[(size_t)n * IN_F + k] * Ws[k * HID + t];
        short hh = f2bf(acc);
        hIL[(size_t)n * ROWW + t] = hh;
        hIL[(size_t)n * ROWW + HID + t] = f2bf(acc - bf2f(hh));
        hSl[((size_t)(t >> 5) * PADN + n) * 32 + (t & 31)] = hh;
    }
}

// -------------------- CSR build: XCD-localized --------------------
__global__ __launch_bounds__(256) void hist8_kernel(
    const int* __restrict__ dst, int* __restrict__ counts8) {
    int e = blockIdx.x * 256 + threadIdx.x;
    int plane = blockIdx.x & 7;
    if (e < N_EDGES) atomicAdd(&counts8[(size_t)plane * N_NODES + dst[e]], 1);
}

__global__ __launch_bounds__(SB) void scan_part1(
    const int* __restrict__ counts8, int* __restrict__ counts,
    int* __restrict__ bsum, int n) {
    __shared__ int s[SB];
    int t = threadIdx.x;
    int i = blockIdx.x * SB + t;
    int v = 0;
    if (i < n) {
#pragma unroll
        for (int p = 0; p < 8; ++p) v += counts8[(size_t)p * N_NODES + i];
        counts[i] = v;
    }
    s[t] = v;
    __syncthreads();
    for (int off = SB / 2; off >= 1; off >>= 1) {
        if (t < off) s[t] += s[t + off];
        __syncthreads();
    }
    if (t == 0) bsum[blockIdx.x] = s[0];
}

__global__ __launch_bounds__(256) void scan_part2(
    const int* __restrict__ bsum, int* __restrict__ boff, int nb) {
    __shared__ int s[256];
    int t = threadIdx.x;
    int v0 = (t < nb) ? bsum[t] : 0;
    s[t] = v0;
    __syncthreads();
    for (int off = 1; off < 256; off <<= 1) {
        int v = (t >= off) ? s[t - off] : 0;
        __syncthreads();
        s[t] += v;
        __syncthreads();
    }
    boff[t] = (t == 0) ? 0 : s[t - 1];
}

__global__ __launch_bounds__(SB) void scan_part3(
    const int* __restrict__ count, const int* __restrict__ boff,
    int* __restrict__ ptr, int* __restrict__ cursor, int n) {
    __shared__ int s[SB];
    int b = blockIdx.x, t = threadIdx.x;
    int i = b * SB + t;
    int v = (i < n) ? count[i] : 0;
    s[t] = v;
    __syncthreads();
    for (int off = 1; off < SB; off <<= 1) {
        int u = (t >= off) ? s[t - off] : 0;
        __syncthreads();
        s[t] += u;
        __syncthreads();
    }
    int excl = s[t] - v + boff[b];
    if (i < n) {
        ptr[i] = excl;
        cursor[i] = excl;
        if (i == n - 1) ptr[n] = excl + v;
    }
}

__global__ __launch_bounds__(256) void scatter8_kernel(
    const int* __restrict__ src, const int* __restrict__ dst,
    int* __restrict__ cursor, int* __restrict__ sorted_src) {
    int s = blockIdx.x & 7;
    int c = blockIdx.x >> 3;
    int lo = s * BINW;
    int hi = lo + BINW;
    int base = c * CHSZ;
    for (int e = base + threadIdx.x; e < base + CHSZ; e += 256) {
        int d = dst[e];
        int sv = src[e];
        if (d >= lo && d < hi) {
            int p = atomicAdd(&cursor[d], 1);
            sorted_src[p] = sv;
        }
    }
}

// -------------------- aggregate v3: slice-pinned, wave-per-node --------------------
// 4 slices x 32 feats (64B H rows, slice-major hSl). Slice (bid&7)>>1 pins each
// slice to an XCD pair -> 3.2MB slice + index stream L2-resident (r6-proven %8 map).
// Wave = 1 node: 4 edge-subsets x 16 lanes, cached per-lane index+data loads,
// unroll-4 (16 edges in flight), end-only shfl_xor reduce. agg2 layout unchanged.
__global__ __launch_bounds__(512) void aggregate_sliced(
    const short* __restrict__ hSl, const int* __restrict__ row_ptr,
    const int* __restrict__ sorted_src, short* __restrict__ agg2) {
    int bid = blockIdx.x;
    int s2 = (bid & 7) >> 1;          // slice 0..3
    int chunk = bid >> 3;
    int wid = threadIdx.x >> 6;
    int lane = threadIdx.x & 63;
    int n = chunk * 8 + wid;
    if (n >= N_NODES) return;
    int g = lane >> 4;                 // edge subset (stride 4)
    int u = lane & 15;                 // dword within 64B slice row
    const unsigned* __restrict__ R = (const unsigned*)hSl + (size_t)s2 * PADN * 16;
    int beg = row_ptr[n], end = row_ptr[n + 1];
    float a0 = 0.f, a1 = 0.f;
#define ACC(v) do { \
        union { unsigned uu; float ff; } q0, q1; \
        q0.uu = (v) << 16; q1.uu = (v) & 0xFFFF0000u; \
        a0 += q0.ff; a1 += q1.ff; } while (0)
    int j = beg + g;
    for (; j + 12 < end; j += 16) {
        int i0 = sorted_src[j];
        int i1 = sorted_src[j + 4];
        int i2 = sorted_src[j + 8];
        int i3 = sorted_src[j + 12];
        unsigned v0 = R[(size_t)i0 * 16 + u];
        unsigned v1 = R[(size_t)i1 * 16 + u];
        unsigned v2 = R[(size_t)i2 * 16 + u];
        unsigned v3 = R[(size_t)i3 * 16 + u];
        ACC(v0); ACC(v1); ACC(v2); ACC(v3);
    }
    for (; j < end; j += 4) {
        int i0 = sorted_src[j];
        unsigned v0 = R[(size_t)i0 * 16 + u];
        ACC(v0);
    }
#undef ACC
    a0 += __shfl_xor(a0, 16); a1 += __shfl_xor(a1, 16);
    a0 += __shfl_xor(a0, 32); a1 += __shfl_xor(a1, 32);
    short h0 = f2bf(a0), h1 = f2bf(a1);
    if (lane < 16) {
        ((unsigned*)agg2)[(size_t)n * 128 + s2 * 16 + u] = pack2(h0, h1);
    } else if (lane < 32) {
        unsigned lw = pack2(f2bf(a0 - bf2f(h0)), f2bf(a1 - bf2f(h1)));
        ((unsigned*)agg2)[(size_t)n * 128 + 64 + s2 * 16 + u] = lw;
    }
}

// -------------------- MFMA layer GEMM: 12 paired A-stages, 20 B tiles --------------------
__global__ __launch_bounds__(512) void layer_gemm_mfma(
    const short* __restrict__ agg2, const short* __restrict__ hIL,
    const short* __restrict__ Bp, const float* __restrict__ bias,
    short* __restrict__ outIL, short* __restrict__ outSl,
    const int* __restrict__ bmap, float* __restrict__ pooled, int layer,
    int write_h) {
    __shared__ __align__(16) char smem[49664];
    short* AbBuf = (short*)smem;             // [2][4096] shorts (16KB)
    short* BbBuf = (short*)(smem + 16384);   // [2][2][4096] shorts (32KB)
    float* Cs    = (float*)smem;             // epilogue: [64][132] fp32 (33792B)
    int*   bmapS = (int*)(smem + 49152);     // 128 ints

    int tid = threadIdx.x;
    int lane = tid & 63;
    int w = tid >> 6;
    int wr = w >> 2, wc = w & 3;   // 2 row-halves x 4 col-quarters
    int m0 = blockIdx.x * BM;

    int r0 = tid >> 2, q0 = tid & 3;   // A chunk: row, kslot (1 chunk/thread)

    f32x4 acc[4][2];
#pragma unroll
    for (int m = 0; m < 4; ++m)
#pragma unroll
        for (int n = 0; n < 2; ++n) acc[m][n] = (f32x4)0.f;

#define NB_OF(a)   (((a) >> 2) == 1 ? 1 : 2)
#define BOFF_OF(a) (((a) < 4) ? (a) * 2 : ((a) < 8) ? 8 + ((a) - 4) : 12 + ((a) - 8) * 2)
#define A_PTR(a)   ((((a) >> 2) <= 1 ? agg2 : hIL) + ((((a) >> 2) == 1) ? HID : 0))

    {   // prologue: stage a=0 (aggH kc0) + B tiles 0,1
        const short* Ap = A_PTR(0);
        short8 a0 = *reinterpret_cast<const short8*>(Ap + (size_t)(m0 + r0) * ROWW + q0 * 8);
        short8 b0 = *reinterpret_cast<const short8*>(Bp + (size_t)tid * 8);
        short8 b1 = *reinterpret_cast<const short8*>(Bp + (size_t)4096 + (size_t)tid * 8);
        *reinterpret_cast<short8*>(&AbBuf[(q0 * 128 + r0) * 8]) = a0;
        *reinterpret_cast<short8*>(&BbBuf[tid * 8]) = b0;
        *reinterpret_cast<short8*>(&BbBuf[4096 + tid * 8]) = b1;
    }
    __syncthreads();

    int kb = lane >> 4;
    int rr = lane & 15;

    for (int a = 0; a < NAST; ++a) {
        int cur = a & 1;
        int nb = NB_OF(a);
        short8 an, bn0, bn1;
        int nbn = 0;
        if (a < NAST - 1) {
            int na = a + 1;
            nbn = NB_OF(na);
            int kc = (na & 3) * 32;
            const short* Ap = A_PTR(na) + kc;
            an = *reinterpret_cast<const short8*>(Ap + (size_t)(m0 + r0) * ROWW + q0 * 8);
            const short* Bsrc = Bp + (size_t)BOFF_OF(na) * 4096;
            bn0 = *reinterpret_cast<const short8*>(Bsrc + (size_t)tid * 8);
            if (nbn == 2)
                bn1 = *reinterpret_cast<const short8*>(Bsrc + (size_t)4096 + (size_t)tid * 8);
        }
        short8 af[4];
#pragma unroll
        for (int m = 0; m < 4; ++m)
            af[m] = *reinterpret_cast<const short8*>(&AbBuf[cur * 4096 + (kb * 128 + wr * 64 + m * 16 + rr) * 8]);
#pragma unroll
        for (int j = 0; j < 2; ++j) {
            if (j < nb) {
                short8 bfr[2];
#pragma unroll
                for (int n = 0; n < 2; ++n)
                    bfr[n] = *reinterpret_cast<const short8*>(
                        &BbBuf[cur * 8192 + j * 4096 + (kb * 128 + wc * 32 + n * 16 + rr) * 8]);
#pragma unroll
                for (int m = 0; m < 4; ++m)
#pragma unroll
                    for (int n = 0; n < 2; ++n)
                        acc[m][n] = __builtin_amdgcn_mfma_f32_16x16x32_bf16(af[m], bfr[n], acc[m][n], 0, 0, 0);
            }
        }
        if (a < NAST - 1) {
            int nxt = cur ^ 1;
            *reinterpret_cast<short8*>(&AbBuf[nxt * 4096 + (q0 * 128 + r0) * 8]) = an;
            *reinterpret_cast<short8*>(&BbBuf[nxt * 8192 + tid * 8]) = bn0;
            if (nbn == 2)
                *reinterpret_cast<short8*>(&BbBuf[nxt * 8192 + 4096 + tid * 8]) = bn1;
        }
        __syncthreads();
    }
#undef NB_OF
#undef BOFF_OF
#undef A_PTR

    // ---- epilogue: two 64-row chunks through LDS ----
    if (tid < 128) {
        int gi = m0 + tid;
        bmapS[tid] = bmap[gi < N_NODES ? gi : N_NODES - 1];
    }
    float bs[2];
    {
        int col = wc * 32 + rr;
#pragma unroll
        for (int n = 0; n < 2; ++n) bs[n] = bias[col + n * 16];
    }
    int colP = tid & 127;     // pooling column
    int quarter = tid >> 7;   // pooling row-quarter (16 rows)

    for (int c = 0; c < 2; ++c) {
        if (wr == c) {
            int colb = wc * 32 + rr;
#pragma unroll
            for (int m = 0; m < 4; ++m) {
#pragma unroll
                for (int n = 0; n < 2; ++n) {
#pragma unroll
                    for (int i = 0; i < 4; ++i) {
                        int lr = m * 16 + kb * 4 + i;
                        Cs[lr * 132 + colb + n * 16] = acc[m][n][i] + bs[n];
                    }
                }
            }
        }
        __syncthreads();

        if (write_h) {
#pragma unroll
            for (int pq = 0; pq < 2; ++pq) {
                int idx = pq * 512 + tid;
                int lr = idx >> 4;
                int oct = idx & 15;
                const float4* crow = reinterpret_cast<const float4*>(&Cs[lr * 132 + oct * 8]);
                float4 c0 = crow[0], c1 = crow[1];
                float v[8] = {c0.x, c0.y, c0.z, c0.w, c1.x, c1.y, c1.z, c1.w};
                unsigned hw[4], lw[4];
#pragma unroll
                for (int k = 0; k < 4; ++k) {
                    short ha = f2bf(v[2 * k]), hb = f2bf(v[2 * k + 1]);
                    short la = f2bf(v[2 * k] - bf2f(ha)), lb = f2bf(v[2 * k + 1] - bf2f(hb));
                    hw[k] = pack2(ha, hb);
                    lw[k] = pack2(la, lb);
                }
                int row = m0 + c * 64 + lr;
                unsigned* oI = (unsigned*)(outIL + (size_t)row * ROWW);
                uint4v hv; hv.x = hw[0]; hv.y = hw[1]; hv.z = hw[2]; hv.w = hw[3];
                uint4v lv; lv.x = lw[0]; lv.y = lw[1]; lv.z = lw[2]; lv.w = lw[3];
                *reinterpret_cast<uint4v*>(oI + oct * 4) = hv;
                *reinterpret_cast<uint4v*>(oI + 64 + oct * 4) = lv;
                // slice-major H copy for the next layer's pinned gather
                int slice = oct >> 2, sub = oct & 3;
                unsigned* oS = (unsigned*)outSl + ((size_t)slice * PADN + row) * 16 + sub * 4;
                *reinterpret_cast<uint4v*>(oS) = hv;
            }
        }

        // pooling: each thread owns one column over 16 rows
        {
            float pacc = 0.f;
            int gprev = -1;
            float* pbase = pooled + (size_t)layer * HID + colP;
            for (int q = 0; q < 16; ++q) {
                int lr = quarter * 16 + q;
                int grow = m0 + c * 64 + lr;
                if (grow >= N_NODES) break;
                int g = bmapS[c * 64 + lr];
                float v = Cs[lr * 132 + colP];
                if (g != gprev) {
                    if (gprev >= 0) atomicAdd(pbase + (size_t)gprev * (DEPTH * HID), pacc);
                    gprev = g; pacc = v;
                } else {
                    pacc += v;
                }
            }
            if (gprev >= 0) atomicAdd(pbase + (size_t)gprev * (DEPTH * HID), pacc);
        }
        __syncthreads();
    }
}

// -------------------- final: out = pooled @ W_sg + b_sg --------------------
__global__ __launch_bounds__(256) void final_kernel(
    const float* __restrict__ pooled, const float* __restrict__ Wsg,
    const float* __restrict__ bsg, float* __restrict__ out) {
    int t = threadIdx.x & 31;
    int g = blockIdx.x * 8 + (threadIdx.x >> 5);
    float acc = bsg[t];
    const float* prow = pooled + (size_t)g * (DEPTH * HID);
    for (int k = 0; k < DEPTH * HID; ++k)
        acc += prow[k] * Wsg[k * IN_F + t];
    out[g * IN_F + t] = acc;
}

extern "C" void kernel_launch(void* const* d_in, const int* in_sizes, int n_in,
                              void* d_out, int out_size, void* d_ws, size_t ws_size,
                              hipStream_t stream) {
    const float* x       = (const float*)d_in[0];
    const int*   edge    = (const int*)d_in[1];
    const int*   bmap    = (const int*)d_in[2];
    // d_in[3] = num_graphs (512); d_in[8]/d_in[9] = W_ws/b_ws dead (softmax over dim-1 == 1)
    const float* W_embed = (const float*)d_in[4];
    const float* W_rel   = (const float*)d_in[5];
    const float* b_rel   = (const float*)d_in[6];
    const float* W_root  = (const float*)d_in[7];
    const float* W_sg    = (const float*)d_in[10];
    const float* b_sg    = (const float*)d_in[11];
    float* out = (float*)d_out;

    const int* src = edge;
    const int* dst = edge + N_EDGES;

    char* ws = (char*)d_ws;
    auto alloc = [&](size_t bytes) -> char* {
        char* p = ws;
        ws += (bytes + 255) & ~(size_t)255;
        return p;
    };
    const size_t rowB = (size_t)PADN * ROWW * 2;   // 25.6 MB interleaved H|L
    const size_t slB  = (size_t)4 * PADN * 32 * 2; // 12.8 MB slice-major H
    short* h_a    = (short*)alloc(rowB);
    short* h_b    = (short*)alloc(rowB);
    short* hSl    = (short*)alloc(slB);            // single buffer: agg(i) reads, gemm(i) rewrites
    short* agg2   = (short*)alloc(rowB);
    float* pooled = (float*)alloc((size_t)N_GRAPHS * DEPTH * HID * 4);
    int* counts8    = (int*)alloc((size_t)8 * N_NODES * 4);
    int* counts     = (int*)alloc((size_t)N_NODES * 4);
    int* row_ptr    = (int*)alloc((size_t)(N_NODES + 1) * 4);
    int* cursor     = (int*)alloc((size_t)N_NODES * 4);
    int* sorted_src = (int*)alloc((size_t)N_EDGES * 4);
    int* bsum       = (int*)alloc((size_t)256 * 4);
    int* boff       = (int*)alloc((size_t)256 * 4);
    short* Bpacked  = (short*)alloc((size_t)PACK_CHUNKS * 8 * 2);

    hipMemsetAsync(counts8, 0, (size_t)8 * N_NODES * 4, stream);
    hipMemsetAsync(pooled, 0, (size_t)N_GRAPHS * DEPTH * HID * 4, stream);

    pack_weights<<<(PACK_CHUNKS + 255) / 256, 256, 0, stream>>>(W_rel, W_root, Bpacked);
    embed_kernel<<<1000, 128, 0, stream>>>(x, W_embed, h_a, hSl);

    hist8_kernel<<<(N_EDGES + 255) / 256, 256, 0, stream>>>(dst, counts8);
    scan_part1<<<NSB, SB, 0, stream>>>(counts8, counts, bsum, N_NODES);
    scan_part2<<<1, 256, 0, stream>>>(bsum, boff, NSB);
    scan_part3<<<NSB, SB, 0, stream>>>(counts, boff, row_ptr, cursor, N_NODES);
    scatter8_kernel<<<NBIN * NCH, 256, 0, stream>>>(src, dst, cursor, sorted_src);

    short *hc = h_a, *hn = h_b;
    for (int i = 0; i < DEPTH; ++i) {
        aggregate_sliced<<<((N_NODES + 7) / 8) * 8, 512, 0, stream>>>(hSl, row_ptr, sorted_src, agg2);
        layer_gemm_mfma<<<GBLK, 512, 0, stream>>>(agg2, hc,
                                                  Bpacked + (size_t)i * NBT * 4096,
                                                  b_rel + (size_t)i * HID,
                                                  hn, hSl, bmap, pooled, i,
                                                  (i < DEPTH - 1) ? 1 : 0);
        short* t = hc; hc = hn; hn = t;
    }

    final_kernel<<<N_GRAPHS / 8, 256, 0, stream>>>(pooled, W_sg, b_sg, out);
}

// Round 13
// 666.542 us; speedup vs baseline: 2.6079x; 2.6079x over previous
//
#include <hip/hip_runtime.h>

#define N_NODES 50000
#define N_EDGES 800000
#define HID 128
#define DEPTH 10
#define N_GRAPHS 512
#define IN_F 32

#define BM 128                       // GEMM rows per block
#define GBLK (50048 / BM)            // 391
#define PADN 50048

#define ROWW 256                     // agg2 row width in shorts: [H 128 | L 128]

#define SB 256                       // scan block size
#define NSB ((N_NODES + SB - 1) / SB)     // 196

#define NBIN 8                       // dst bins == XCDs
#define BINW ((N_NODES + NBIN - 1) / NBIN)   // 6250
#define NCH 500                      // edge chunks per bin
#define CHSZ (N_EDGES / NCH)         // 1600

#define NBT 20                       // B tiles per layer (5 terms x 4 kc)
#define NAST 12                      // A stages (3 planes x 4 kc): aggH, aggL, hH
#define PACK_CHUNKS (DEPTH * NBT * 512)

typedef __attribute__((ext_vector_type(8))) short short8;
typedef __attribute__((ext_vector_type(4))) float f32x4;
typedef __attribute__((ext_vector_type(4))) unsigned uint4v;

__device__ __forceinline__ float bf2f(short u) {
    union { unsigned i; float f; } v; v.i = ((unsigned)(unsigned short)u) << 16; return v.f;
}
__device__ __forceinline__ short f2bf(float f) {
    union { float f; unsigned i; } v; v.f = f;
    unsigned r = (v.i + 0x7FFFu + ((v.i >> 16) & 1u)) >> 16;
    return (short)r;
}
__device__ __forceinline__ unsigned pack2(short lo, short hi) {
    return ((unsigned)(unsigned short)hi << 16) | (unsigned)(unsigned short)lo;
}

// -------------------- weight pack: per-A-stage B-tile order --------------------
// Tiles t (0..19): t<8:  (rel,  kc=t>>1,      lo=t&1)   [aggH stages: relH,relL]
//                  8-11: (rel,  kc=t-8,       lo=0)     [aggL stages: relH]
//                  12-19:(root, kc=(t-12)>>1, lo=t&1)   [hH stages: rootH,rootL]
__global__ __launch_bounds__(256) void pack_weights(
    const float* __restrict__ Wrel, const float* __restrict__ Wroot,
    short* __restrict__ Bp) {
    int idx = blockIdx.x * 256 + threadIdx.x;
    if (idx >= PACK_CHUNKS) return;
    int layer = idx / (NBT * 512);
    int rem = idx - layer * NBT * 512;
    int t = rem >> 9;
    int c = rem & 511;
    int kslot = c >> 7, n = c & 127;
    int kc, lo;
    const float* W;
    if (t < 8)       { kc = t >> 1;        W = Wrel;  lo = t & 1; }
    else if (t < 12) { kc = t - 8;         W = Wrel;  lo = 0; }
    else             { kc = (t - 12) >> 1; W = Wroot; lo = t & 1; }
    W += (size_t)layer * HID * HID;
    short out[8];
#pragma unroll
    for (int j = 0; j < 8; ++j) {
        int k = kc * 32 + kslot * 8 + j;
        float v = W[(size_t)k * HID + n];
        short hi = f2bf(v);
        if (lo) { v = v - bf2f(hi); hi = f2bf(v); }
        out[j] = hi;
    }
    *reinterpret_cast<short8*>(Bp + (size_t)idx * 8) = *reinterpret_cast<short8*>(out);
}

// -------------------- embed: h = x @ W_embed -> H-only rows --------------------
__global__ __launch_bounds__(128) void embed_kernel(
    const float* __restrict__ x, const float* __restrict__ W,
    short* __restrict__ h) {
    __shared__ float Ws[IN_F * HID];
    int t = threadIdx.x;
    for (int i = t; i < IN_F * HID; i += 128) Ws[i] = W[i];
    __syncthreads();
    int nbeg = blockIdx.x * 50;
    for (int n = nbeg; n < nbeg + 50; ++n) {
        float acc = 0.f;
#pragma unroll
        for (int k = 0; k < IN_F; ++k)
            acc += x[(size_t)n * IN_F + k] * Ws[k * HID + t];
        h[(size_t)n * HID + t] = f2bf(acc);
    }
}

// -------------------- CSR build: XCD-localized --------------------
__global__ __launch_bounds__(256) void hist8_kernel(
    const int* __restrict__ dst, int* __restrict__ counts8) {
    int e = blockIdx.x * 256 + threadIdx.x;
    int plane = blockIdx.x & 7;
    if (e < N_EDGES) atomicAdd(&counts8[(size_t)plane * N_NODES + dst[e]], 1);
}

__global__ __launch_bounds__(SB) void scan_part1(
    const int* __restrict__ counts8, int* __restrict__ counts,
    int* __restrict__ bsum, int n) {
    __shared__ int s[SB];
    int t = threadIdx.x;
    int i = blockIdx.x * SB + t;
    int v = 0;
    if (i < n) {
#pragma unroll
        for (int p = 0; p < 8; ++p) v += counts8[(size_t)p * N_NODES + i];
        counts[i] = v;
    }
    s[t] = v;
    __syncthreads();
    for (int off = SB / 2; off >= 1; off >>= 1) {
        if (t < off) s[t] += s[t + off];
        __syncthreads();
    }
    if (t == 0) bsum[blockIdx.x] = s[0];
}

__global__ __launch_bounds__(256) void scan_part2(
    const int* __restrict__ bsum, int* __restrict__ boff, int nb) {
    __shared__ int s[256];
    int t = threadIdx.x;
    int v0 = (t < nb) ? bsum[t] : 0;
    s[t] = v0;
    __syncthreads();
    for (int off = 1; off < 256; off <<= 1) {
        int v = (t >= off) ? s[t - off] : 0;
        __syncthreads();
        s[t] += v;
        __syncthreads();
    }
    boff[t] = (t == 0) ? 0 : s[t - 1];
}

__global__ __launch_bounds__(SB) void scan_part3(
    const int* __restrict__ count, const int* __restrict__ boff,
    int* __restrict__ ptr, int* __restrict__ cursor, int n) {
    __shared__ int s[SB];
    int b = blockIdx.x, t = threadIdx.x;
    int i = b * SB + t;
    int v = (i < n) ? count[i] : 0;
    s[t] = v;
    __syncthreads();
    for (int off = 1; off < SB; off <<= 1) {
        int u = (t >= off) ? s[t - off] : 0;
        __syncthreads();
        s[t] += u;
        __syncthreads();
    }
    int excl = s[t] - v + boff[b];
    if (i < n) {
        ptr[i] = excl;
        cursor[i] = excl;
        if (i == n - 1) ptr[n] = excl + v;
    }
}

__global__ __launch_bounds__(256) void scatter8_kernel(
    const int* __restrict__ src, const int* __restrict__ dst,
    int* __restrict__ cursor, int* __restrict__ sorted_src) {
    int s = blockIdx.x & 7;
    int c = blockIdx.x >> 3;
    int lo = s * BINW;
    int hi = lo + BINW;
    int base = c * CHSZ;
    for (int e = base + threadIdx.x; e < base + CHSZ; e += 256) {
        int d = dst[e];
        int sv = src[e];
        if (d >= lo && d < hi) {
            int p = atomicAdd(&cursor[d], 1);
            sorted_src[p] = sv;
        }
    }
}

// -------------------- aggregate: wave-per-node, 256B H-row gather (r11 schedule) ----
__global__ __launch_bounds__(256) void aggregate_kernel(
    const short* __restrict__ h, const int* __restrict__ row_ptr,
    const int* __restrict__ sorted_src, short* __restrict__ agg2) {
    int n = (blockIdx.x * 256 + threadIdx.x) >> 6;
    int lane = threadIdx.x & 63;
    const unsigned* __restrict__ R = (const unsigned*)h;  // 64 dwords per row
    int beg = row_ptr[n], end = row_ptr[n + 1];
    float a0 = 0.f, a1 = 0.f;
#define ACC(v) do { \
        union { unsigned u; float f; } u0, u1; \
        u0.u = (v) << 16; u1.u = (v) & 0xFFFF0000u; \
        a0 += u0.f; a1 += u1.f; } while (0)
    int j = beg;
    for (; j + 8 <= end; j += 8) {
        unsigned v[8];
#pragma unroll
        for (int u = 0; u < 8; ++u) {
            int s = __builtin_amdgcn_readfirstlane(sorted_src[j + u]);
            v[u] = R[(size_t)s * 64 + lane];
        }
#pragma unroll
        for (int u = 0; u < 8; ++u) ACC(v[u]);
    }
    for (; j + 2 <= end; j += 2) {
        int s0 = __builtin_amdgcn_readfirstlane(sorted_src[j]);
        int s1 = __builtin_amdgcn_readfirstlane(sorted_src[j + 1]);
        unsigned v0 = R[(size_t)s0 * 64 + lane];
        unsigned v1 = R[(size_t)s1 * 64 + lane];
        ACC(v0); ACC(v1);
    }
    if (j < end) {
        int s = __builtin_amdgcn_readfirstlane(sorted_src[j]);
        unsigned v = R[(size_t)s * 64 + lane];
        ACC(v);
    }
#undef ACC
    short h0 = f2bf(a0), h1 = f2bf(a1);
    unsigned hw = pack2(h0, h1);
    unsigned lw = pack2(f2bf(a0 - bf2f(h0)), f2bf(a1 - bf2f(h1)));
    ((unsigned*)agg2)[(size_t)n * 128 + lane] = hw;
    ((unsigned*)agg2)[(size_t)n * 128 + 64 + lane] = lw;
}

// -------------------- MFMA layer GEMM: 12 paired A-stages, 20 B tiles --------------------
// A-stage a: plane = a>>2 (0:aggH 1:aggL 2:hH), kc = a&3; aggH/hH stages run
// 2 B tiles each, aggL 1 -> each A byte read once from global (38.4MB/layer).
// h is H-only [PADN][HID]; epilogue writes H only (dead L write removed).
__global__ __launch_bounds__(512) void layer_gemm_mfma(
    const short* __restrict__ agg2, const short* __restrict__ h,
    const short* __restrict__ Bp, const float* __restrict__ bias,
    short* __restrict__ outH,
    const int* __restrict__ bmap, float* __restrict__ pooled, int layer,
    int write_h) {
    __shared__ __align__(16) char smem[49664];
    short* AbBuf = (short*)smem;             // [2][4096] shorts (16KB)
    short* BbBuf = (short*)(smem + 16384);   // [2][2][4096] shorts (32KB)
    float* Cs    = (float*)smem;             // epilogue: [64][132] fp32 (33792B)
    int*   bmapS = (int*)(smem + 49152);     // 128 ints

    int tid = threadIdx.x;
    int lane = tid & 63;
    int w = tid >> 6;
    int wr = w >> 2, wc = w & 3;   // 2 row-halves x 4 col-quarters
    int m0 = blockIdx.x * BM;

    int r0 = tid >> 2, q0 = tid & 3;   // A chunk: row, kslot (1 chunk/thread)

    f32x4 acc[4][2];
#pragma unroll
    for (int m = 0; m < 4; ++m)
#pragma unroll
        for (int n = 0; n < 2; ++n) acc[m][n] = (f32x4)0.f;

#define NB_OF(a)   (((a) >> 2) == 1 ? 1 : 2)
#define BOFF_OF(a) (((a) < 4) ? (a) * 2 : ((a) < 8) ? 8 + ((a) - 4) : 12 + ((a) - 8) * 2)

    {   // prologue: stage a=0 (aggH kc0) + B tiles 0,1
        short8 a0 = *reinterpret_cast<const short8*>(agg2 + (size_t)(m0 + r0) * ROWW + q0 * 8);
        short8 b0 = *reinterpret_cast<const short8*>(Bp + (size_t)tid * 8);
        short8 b1 = *reinterpret_cast<const short8*>(Bp + (size_t)4096 + (size_t)tid * 8);
        *reinterpret_cast<short8*>(&AbBuf[(q0 * 128 + r0) * 8]) = a0;
        *reinterpret_cast<short8*>(&BbBuf[tid * 8]) = b0;
        *reinterpret_cast<short8*>(&BbBuf[4096 + tid * 8]) = b1;
    }
    __syncthreads();

    int kb = lane >> 4;
    int rr = lane & 15;

    for (int a = 0; a < NAST; ++a) {
        int cur = a & 1;
        int nb = NB_OF(a);
        short8 an, bn0, bn1;
        int nbn = 0;
        if (a < NAST - 1) {
            int na = a + 1;
            nbn = NB_OF(na);
            int kc = (na & 3) * 32;
            if (na >= 8) {   // hH plane: compact H-only buffer, stride HID
                an = *reinterpret_cast<const short8*>(h + (size_t)(m0 + r0) * HID + kc + q0 * 8);
            } else {         // agg planes: interleaved rows, stride ROWW
                const short* Ap = agg2 + (((na >> 2) == 1) ? HID : 0) + kc;
                an = *reinterpret_cast<const short8*>(Ap + (size_t)(m0 + r0) * ROWW + q0 * 8);
            }
            const short* Bsrc = Bp + (size_t)BOFF_OF(na) * 4096;
            bn0 = *reinterpret_cast<const short8*>(Bsrc + (size_t)tid * 8);
            if (nbn == 2)
                bn1 = *reinterpret_cast<const short8*>(Bsrc + (size_t)4096 + (size_t)tid * 8);
        }
        short8 af[4];
#pragma unroll
        for (int m = 0; m < 4; ++m)
            af[m] = *reinterpret_cast<const short8*>(&AbBuf[cur * 4096 + (kb * 128 + wr * 64 + m * 16 + rr) * 8]);
#pragma unroll
        for (int j = 0; j < 2; ++j) {
            if (j < nb) {
                short8 bfr[2];
#pragma unroll
                for (int n = 0; n < 2; ++n)
                    bfr[n] = *reinterpret_cast<const short8*>(
                        &BbBuf[cur * 8192 + j * 4096 + (kb * 128 + wc * 32 + n * 16 + rr) * 8]);
#pragma unroll
                for (int m = 0; m < 4; ++m)
#pragma unroll
                    for (int n = 0; n < 2; ++n)
                        acc[m][n] = __builtin_amdgcn_mfma_f32_16x16x32_bf16(af[m], bfr[n], acc[m][n], 0, 0, 0);
            }
        }
        if (a < NAST - 1) {
            int nxt = cur ^ 1;
            *reinterpret_cast<short8*>(&AbBuf[nxt * 4096 + (q0 * 128 + r0) * 8]) = an;
            *reinterpret_cast<short8*>(&BbBuf[nxt * 8192 + tid * 8]) = bn0;
            if (nbn == 2)
                *reinterpret_cast<short8*>(&BbBuf[nxt * 8192 + 4096 + tid * 8]) = bn1;
        }
        __syncthreads();
    }
#undef NB_OF
#undef BOFF_OF

    // ---- epilogue: two 64-row chunks through LDS ----
    if (tid < 128) {
        int gi = m0 + tid;
        bmapS[tid] = bmap[gi < N_NODES ? gi : N_NODES - 1];
    }
    float bs[2];
    {
        int col = wc * 32 + rr;
#pragma unroll
        for (int n = 0; n < 2; ++n) bs[n] = bias[col + n * 16];
    }
    int colP = tid & 127;     // pooling column
    int quarter = tid >> 7;   // pooling row-quarter (16 rows)

    for (int c = 0; c < 2; ++c) {
        if (wr == c) {
            int colb = wc * 32 + rr;
#pragma unroll
            for (int m = 0; m < 4; ++m) {
#pragma unroll
                for (int n = 0; n < 2; ++n) {
#pragma unroll
                    for (int i = 0; i < 4; ++i) {
                        int lr = m * 16 + kb * 4 + i;
                        Cs[lr * 132 + colb + n * 16] = acc[m][n][i] + bs[n];
                    }
                }
            }
        }
        __syncthreads();

        if (write_h) {
#pragma unroll
            for (int pq = 0; pq < 2; ++pq) {
                int idx = pq * 512 + tid;
                int lr = idx >> 4;
                int oct = idx & 15;
                const float4* crow = reinterpret_cast<const float4*>(&Cs[lr * 132 + oct * 8]);
                float4 c0 = crow[0], c1 = crow[1];
                float v[8] = {c0.x, c0.y, c0.z, c0.w, c1.x, c1.y, c1.z, c1.w};
                unsigned hw[4];
#pragma unroll
                for (int k = 0; k < 4; ++k)
                    hw[k] = pack2(f2bf(v[2 * k]), f2bf(v[2 * k + 1]));
                int row = m0 + c * 64 + lr;
                unsigned* oH = (unsigned*)(outH + (size_t)row * HID);
                uint4v hv; hv.x = hw[0]; hv.y = hw[1]; hv.z = hw[2]; hv.w = hw[3];
                *reinterpret_cast<uint4v*>(oH + oct * 4) = hv;
            }
        }

        // pooling: each thread owns one column over 16 rows
        {
            float pacc = 0.f;
            int gprev = -1;
            float* pbase = pooled + (size_t)layer * HID + colP;
            for (int q = 0; q < 16; ++q) {
                int lr = quarter * 16 + q;
                int grow = m0 + c * 64 + lr;
                if (grow >= N_NODES) break;
                int g = bmapS[c * 64 + lr];
                float v = Cs[lr * 132 + colP];
                if (g != gprev) {
                    if (gprev >= 0) atomicAdd(pbase + (size_t)gprev * (DEPTH * HID), pacc);
                    gprev = g; pacc = v;
                } else {
                    pacc += v;
                }
            }
            if (gprev >= 0) atomicAdd(pbase + (size_t)gprev * (DEPTH * HID), pacc);
        }
        __syncthreads();
    }
}

// -------------------- final: out = pooled @ W_sg + b_sg --------------------
__global__ __launch_bounds__(256) void final_kernel(
    const float* __restrict__ pooled, const float* __restrict__ Wsg,
    const float* __restrict__ bsg, float* __restrict__ out) {
    int t = threadIdx.x & 31;
    int g = blockIdx.x * 8 + (threadIdx.x >> 5);
    float acc = bsg[t];
    const float* prow = pooled + (size_t)g * (DEPTH * HID);
    for (int k = 0; k < DEPTH * HID; ++k)
        acc += prow[k] * Wsg[k * IN_F + t];
    out[g * IN_F + t] = acc;
}

extern "C" void kernel_launch(void* const* d_in, const int* in_sizes, int n_in,
                              void* d_out, int out_size, void* d_ws, size_t ws_size,
                              hipStream_t stream) {
    const float* x       = (const float*)d_in[0];
    const int*   edge    = (const int*)d_in[1];
    const int*   bmap    = (const int*)d_in[2];
    // d_in[3] = num_graphs (512); d_in[8]/d_in[9] = W_ws/b_ws dead (softmax over dim-1 == 1)
    const float* W_embed = (const float*)d_in[4];
    const float* W_rel   = (const float*)d_in[5];
    const float* b_rel   = (const float*)d_in[6];
    const float* W_root  = (const float*)d_in[7];
    const float* W_sg    = (const float*)d_in[10];
    const float* b_sg    = (const float*)d_in[11];
    float* out = (float*)d_out;

    const int* src = edge;
    const int* dst = edge + N_EDGES;

    char* ws = (char*)d_ws;
    auto alloc = [&](size_t bytes) -> char* {
        char* p = ws;
        ws += (bytes + 255) & ~(size_t)255;
        return p;
    };
    const size_t rowB = (size_t)PADN * ROWW * 2;   // 25.6 MB interleaved H|L (agg2)
    const size_t hB   = (size_t)PADN * HID * 2;    // 12.8 MB H-only h
    short* h_a    = (short*)alloc(hB);
    short* h_b    = (short*)alloc(hB);
    short* agg2   = (short*)alloc(rowB);
    float* pooled = (float*)alloc((size_t)N_GRAPHS * DEPTH * HID * 4);
    int* counts8    = (int*)alloc((size_t)8 * N_NODES * 4);
    int* counts     = (int*)alloc((size_t)N_NODES * 4);
    int* row_ptr    = (int*)alloc((size_t)(N_NODES + 1) * 4);
    int* cursor     = (int*)alloc((size_t)N_NODES * 4);
    int* sorted_src = (int*)alloc((size_t)N_EDGES * 4);
    int* bsum       = (int*)alloc((size_t)256 * 4);
    int* boff       = (int*)alloc((size_t)256 * 4);
    short* Bpacked  = (short*)alloc((size_t)PACK_CHUNKS * 8 * 2);

    hipMemsetAsync(counts8, 0, (size_t)8 * N_NODES * 4, stream);
    hipMemsetAsync(pooled, 0, (size_t)N_GRAPHS * DEPTH * HID * 4, stream);

    pack_weights<<<(PACK_CHUNKS + 255) / 256, 256, 0, stream>>>(W_rel, W_root, Bpacked);
    embed_kernel<<<1000, 128, 0, stream>>>(x, W_embed, h_a);

    hist8_kernel<<<(N_EDGES + 255) / 256, 256, 0, stream>>>(dst, counts8);
    scan_part1<<<NSB, SB, 0, stream>>>(counts8, counts, bsum, N_NODES);
    scan_part2<<<1, 256, 0, stream>>>(bsum, boff, NSB);
    scan_part3<<<NSB, SB, 0, stream>>>(counts, boff, row_ptr, cursor, N_NODES);
    scatter8_kernel<<<NBIN * NCH, 256, 0, stream>>>(src, dst, cursor, sorted_src);

    short *hc = h_a, *hn = h_b;
    for (int i = 0; i < DEPTH; ++i) {
        aggregate_kernel<<<(N_NODES + 3) / 4, 256, 0, stream>>>(hc, row_ptr, sorted_src, agg2);
        layer_gemm_mfma<<<GBLK, 512, 0, stream>>>(agg2, hc,
                                                  Bpacked + (size_t)i * NBT * 4096,
                                                  b_rel + (size_t)i * HID,
                                                  hn, bmap, pooled, i,
                                                  (i < DEPTH - 1) ? 1 : 0);
        short* t = hc; hc = hn; hn = t;
    }

    final_kernel<<<N_GRAPHS / 8, 256, 0, stream>>>(pooled, W_sg, b_sg, out);
}